// Round 1
// baseline (2595.304 us; speedup 1.0000x reference)
//
#include <hip/hip_runtime.h>
#include <math.h>

#define BATCH 256
#define NNODE 128
#define NT    32768      // BATCH*NNODE
#define FDIM  128
#define NEDGE 262144
#define LBL   29
#define MAXDEG 16
#define RWD   16
#define NTF   (NT * FDIM)   // 4194304 elements per feature matrix

// ---------------------------------------------------------------- init feat
// out[i][f] = relu(b[f] + sum_k concat(x_i, demb[cent_i], rw_i)[k] * W[k][f])
__global__ __launch_bounds__(256) void k_init_feat(
    const float* __restrict__ x, const int* __restrict__ cent,
    const float* __restrict__ rw, const float* __restrict__ demb,
    const float* __restrict__ W, const float* __restrict__ b,
    float* __restrict__ out) {
  int gid = blockIdx.x * 256 + threadIdx.x;      // NT*FDIM threads
  int row = gid >> 7, f = gid & 127;
  const float* xr = x + row * LBL;
  const float* er = demb + cent[row] * MAXDEG;
  const float* rr = rw + row * RWD;
  float acc = b[f];
#pragma unroll
  for (int k = 0; k < LBL; ++k)    acc += xr[k] * W[k * FDIM + f];
#pragma unroll
  for (int k = 0; k < MAXDEG; ++k) acc += er[k] * W[(LBL + k) * FDIM + f];
#pragma unroll
  for (int k = 0; k < RWD; ++k)    acc += rr[k] * W[(LBL + MAXDEG + k) * FDIM + f];
  out[gid] = fmaxf(acc, 0.f);
}

// ---------------------------------------------------------------- helpers
__global__ void k_fill(float* __restrict__ p, float v, int n) {
  int i = blockIdx.x * 256 + threadIdx.x;
  if (i < n) p[i] = v;
}
__global__ void k_deg_scatter(const int* __restrict__ dst, float* __restrict__ deg) {
  int e = blockIdx.x * 256 + threadIdx.x;
  if (e < NEDGE) atomicAdd(&deg[dst[e]], 1.f);
}
__global__ void k_rsq(float* __restrict__ p, int n) {
  int i = blockIdx.x * 256 + threadIdx.x;
  if (i < n) p[i] = rsqrtf(fmaxf(p[i], 1.f));
}

// ---------------------------------------------------------------- dense mm
// out (NT x 128) = relu?(A) (NT x 128) @ W (128 x 128)
template <bool RELU_IN>
__global__ __launch_bounds__(256) void k_mm(const float* __restrict__ A,
                                            const float* __restrict__ W,
                                            float* __restrict__ out) {
  int gid = blockIdx.x * 256 + threadIdx.x;
  int row = gid >> 7, f = gid & 127;
  const float* ar = A + row * FDIM;
  float acc = 0.f;
#pragma unroll 8
  for (int k = 0; k < FDIM; ++k) {
    float a = ar[k];
    if (RELU_IN) a = fmaxf(a, 0.f);
    acc += a * W[k * FDIM + f];
  }
  out[gid] = acc;
}

// ---------------------------------------------------------------- gcn agg
__global__ __launch_bounds__(256) void k_agg_init(
    const float* __restrict__ h, const float* __restrict__ dinv,
    const float* __restrict__ b, float* __restrict__ out) {
  int gid = blockIdx.x * 256 + threadIdx.x;
  int row = gid >> 7, f = gid & 127;
  float di = dinv[row];
  out[gid] = b[f] + di * di * h[gid];
}
__global__ __launch_bounds__(256) void k_agg_scatter(
    const float* __restrict__ h, const int* __restrict__ src,
    const int* __restrict__ dst, const float* __restrict__ dinv,
    float* __restrict__ out) {
  int gid = blockIdx.x * 256 + threadIdx.x;   // NEDGE*FDIM threads
  int e = gid >> 7, f = gid & 127;
  int s = src[e], d = dst[e];
  float w = dinv[s] * dinv[d];
  atomicAdd(&out[d * FDIM + f], h[s * FDIM + f] * w);
}

// ---------------------------------------------------------------- pooling
__global__ __launch_bounds__(128) void k_pool_sum(const float* __restrict__ m,
                                                  float* __restrict__ gfs, int colofs) {
  int b = blockIdx.x, c = threadIdx.x;   // 128 threads
  const float* base = m + (size_t)b * NNODE * FDIM + c;
  float s = 0.f;
  for (int n = 0; n < NNODE; ++n) s += base[n * FDIM];
  gfs[b * 1024 + colofs + c] = s;
}
__global__ __launch_bounds__(128) void k_pool_max(const float* __restrict__ m,
                                                  float* __restrict__ gfs, int colofs) {
  int b = blockIdx.x, c = threadIdx.x;
  const float* base = m + (size_t)b * NNODE * FDIM + c;
  float s = -INFINITY;
  for (int n = 0; n < NNODE; ++n) s = fmaxf(s, base[n * FDIM]);
  gfs[b * 1024 + colofs + c] = s;
}

// ---------------------------------------------------------------- affinity S[b] = Y[b] @ X[b]^T
__global__ __launch_bounds__(256) void k_affS(const float* __restrict__ Y,
                                              const float* __restrict__ X,
                                              float* __restrict__ S) {
  __shared__ float xs[64 * 129];   // 64 j-rows, padded stride
  int b = blockIdx.x, t = threadIdx.x;
  const float* Yb = Y + (size_t)b * NNODE * FDIM;
  const float* Xb = X + (size_t)b * NNODE * FDIM;
  float* Sb = S + (size_t)b * NNODE * NNODE;
  for (int tile = 0; tile < 2; ++tile) {
    int jbase = tile * 64;
    __syncthreads();
    for (int u = t; u < 64 * FDIM; u += 256) {
      int r = u >> 7, c = u & 127;
      xs[r * 129 + c] = Xb[(jbase + r) * FDIM + c];
    }
    __syncthreads();
    for (int u = 0; u < 32; ++u) {
      int v = t + 256 * u;      // 0..8191
      int i = v >> 6;           // wave-uniform
      int j = v & 63;
      const float* yr = Yb + i * FDIM;
      const float* xr = xs + j * 129;
      float acc = 0.f;
#pragma unroll 8
      for (int k = 0; k < FDIM; ++k) acc += yr[k] * xr[k];
      Sb[i * NNODE + jbase + j] = acc;
    }
  }
}

// ---------------------------------------------------------------- sinkhorn soft-topk (in place)
__global__ __launch_bounds__(256) void k_sinkhorn(float* __restrict__ S,
                                                  const int* __restrict__ topk) {
  const int L = NNODE * NNODE;           // 16384
  int b = blockIdx.x, t = threadIdx.x;
  int wave = t >> 6, lane = t & 63;
  float* x = S + (size_t)b * L;

  __shared__ float red[8];
  __shared__ float bc[2];
  __shared__ float rm[8], rs[8];

  float xv[64];
#pragma unroll
  for (int u = 0; u < 64; ++u) xv[u] = x[t + 256 * u];

  // min / max
  float mn = xv[0], mx = xv[0];
#pragma unroll
  for (int u = 1; u < 64; ++u) { mn = fminf(mn, xv[u]); mx = fmaxf(mx, xv[u]); }
  for (int off = 32; off > 0; off >>= 1) {
    mn = fminf(mn, __shfl_down(mn, off));
    mx = fmaxf(mx, __shfl_down(mx, off));
  }
  if (lane == 0) { red[wave] = mn; red[4 + wave] = mx; }
  __syncthreads();
  if (t == 0) {
    float a = fminf(fminf(red[0], red[1]), fminf(red[2], red[3]));
    float c = fmaxf(fmaxf(red[4], red[5]), fmaxf(red[6], red[7]));
    bc[0] = a - 1.f; bc[1] = c + 1.f;
  }
  __syncthreads();
  float a_lo = bc[0], a_hi = bc[1];

  float kk = 0.5f * (float)topk[0];
  const float log_mu = -logf((float)L);
  float log_nu0 = logf(((float)L - kk) / (float)L);
  float log_nu1 = logf(kk / (float)L);

  float g0 = 0.f, g1 = 0.f, gp0 = 0.f, gp1 = 0.f;
  for (int it = 0; it < 6; ++it) {
    gp0 = g0; gp1 = g1;
    float m0 = -INFINITY, s0 = 0.f, m1 = -INFINITY, s1 = 0.f;
#pragma unroll
    for (int u = 0; u < 64; ++u) {
      float xi = xv[u];
      float k0 = a_lo - xi;         // logK[i][0]
      float k1 = xi - a_hi;         // logK[i][1]
      float t0 = k0 + g0, t1 = k1 + g1;
      float mm = fmaxf(t0, t1);
      float f = log_mu - (mm + logf(expf(t0 - mm) + expf(t1 - mm)));
      float e0 = k0 + f, e1 = k1 + f;
      if (e0 > m0) { s0 = s0 * expf(m0 - e0) + 1.f; m0 = e0; } else s0 += expf(e0 - m0);
      if (e1 > m1) { s1 = s1 * expf(m1 - e1) + 1.f; m1 = e1; } else s1 += expf(e1 - m1);
    }
    for (int off = 32; off > 0; off >>= 1) {
      float om = __shfl_down(m0, off), os = __shfl_down(s0, off);
      float M = fmaxf(m0, om);
      s0 = s0 * expf(m0 - M) + os * expf(om - M); m0 = M;
      om = __shfl_down(m1, off); os = __shfl_down(s1, off);
      M = fmaxf(m1, om);
      s1 = s1 * expf(m1 - M) + os * expf(om - M); m1 = M;
    }
    if (lane == 0) { rm[wave] = m0; rs[wave] = s0; rm[4 + wave] = m1; rs[4 + wave] = s1; }
    __syncthreads();
    if (t == 0) {
      float M0 = fmaxf(fmaxf(rm[0], rm[1]), fmaxf(rm[2], rm[3]));
      float S0 = rs[0] * expf(rm[0] - M0) + rs[1] * expf(rm[1] - M0) +
                 rs[2] * expf(rm[2] - M0) + rs[3] * expf(rm[3] - M0);
      float M1 = fmaxf(fmaxf(rm[4], rm[5]), fmaxf(rm[6], rm[7]));
      float S1 = rs[4] * expf(rm[4] - M1) + rs[5] * expf(rm[5] - M1) +
                 rs[6] * expf(rm[6] - M1) + rs[7] * expf(rm[7] - M1);
      bc[0] = log_nu0 - (M0 + logf(S0));
      bc[1] = log_nu1 - (M1 + logf(S1));
    }
    __syncthreads();
    g0 = bc[0]; g1 = bc[1];
    __syncthreads();
  }
  // prob = exp(logK1 + f(g_prev) + g1_final) * L   (f uses g BEFORE last update)
  const float Lf = (float)L;
#pragma unroll
  for (int u = 0; u < 64; ++u) {
    float xi = xv[u];
    float k0 = a_lo - xi, k1 = xi - a_hi;
    float t0 = k0 + gp0, t1 = k1 + gp1;
    float mm = fmaxf(t0, t1);
    float f = log_mu - (mm + logf(expf(t0 - mm) + expf(t1 - mm)));
    x[t + 256 * u] = expf(k1 + f + g1) * Lf;
  }
}

// ---------------------------------------------------------------- scoring MLP
__global__ __launch_bounds__(64) void k_mlp(const float* __restrict__ gfs,
                                            const float* __restrict__ W1,
                                            const float* __restrict__ b1,
                                            const float* __restrict__ W2,
                                            const float* __restrict__ b2,
                                            float* __restrict__ ged) {
  int b = blockIdx.x, j = threadIdx.x;   // 64 threads = 1 wave
  const float* s = gfs + b * 1024;
  float acc = b1[j];
  for (int k = 0; k < 1024; ++k) acc += s[k] * W1[k * 64 + j];
  float h = fmaxf(acc, 0.f);
  float v = h * W2[j];
  for (int off = 32; off > 0; off >>= 1) v += __shfl_down(v, off);
  if (j == 0) ged[b] = 1.f / (1.f + expf(-(v + b2[0])));
}

// ================================================================ launch
extern "C" void kernel_launch(void* const* d_in, const int* in_sizes, int n_in,
                              void* d_out, int out_size, void* d_ws, size_t ws_size,
                              hipStream_t stream) {
  (void)in_sizes; (void)n_in; (void)out_size; (void)ws_size;
  const float* x1    = (const float*)d_in[0];
  const int*   cent1 = (const int*)  d_in[1];
  const float* rw1   = (const float*)d_in[2];
  const int*   src1  = (const int*)  d_in[3];
  const int*   dst1  = (const int*)  d_in[4];
  const float* x2    = (const float*)d_in[5];
  const int*   cent2 = (const int*)  d_in[6];
  const float* rw2   = (const float*)d_in[7];
  const int*   src2  = (const int*)  d_in[8];
  const int*   dst2  = (const int*)  d_in[9];
  const float* demb  = (const float*)d_in[10];
  const float* initW = (const float*)d_in[11];
  const float* initb = (const float*)d_in[12];
  const float* W1    = (const float*)d_in[13];
  const float* b1    = (const float*)d_in[14];
  const float* W2    = (const float*)d_in[15];
  const float* b2    = (const float*)d_in[16];
  const float* W3    = (const float*)d_in[17];
  const float* b3    = (const float*)d_in[18];
  const float* Aaff  = (const float*)d_in[19];
  const float* scW1  = (const float*)d_in[20];
  const float* scb1  = (const float*)d_in[21];
  const float* scW2  = (const float*)d_in[22];
  const float* scb2  = (const float*)d_in[23];
  const int*   topk  = (const int*)  d_in[24];

  float* ws    = (float*)d_ws;
  float* feat1 = ws;
  float* feat2 = ws + (size_t)1 * NTF;
  float* tA    = ws + (size_t)2 * NTF;
  float* tB    = ws + (size_t)3 * NTF;
  float* f13   = ws + (size_t)4 * NTF;
  float* f23   = ws + (size_t)5 * NTF;
  float* htmp  = ws + (size_t)6 * NTF;   // also reused as Y
  float* dinv1 = ws + (size_t)7 * NTF;
  float* dinv2 = dinv1 + NT;
  float* gfs   = dinv2 + NT;             // 256*1024

  float* ged = (float*)d_out;
  float* S1  = ged + BATCH;
  float* S2  = S1 + (size_t)BATCH * NNODE * NNODE;

  const int gElem = NT * FDIM / 256;     // 16384 blocks
  const int gScat = NEDGE * FDIM / 256;  // 131072 blocks

  // init features
  k_init_feat<<<gElem, 256, 0, stream>>>(x1, cent1, rw1, demb, initW, initb, feat1);
  k_init_feat<<<gElem, 256, 0, stream>>>(x2, cent2, rw2, demb, initW, initb, feat2);

  // degree norms
  k_fill<<<NT / 256, 256, 0, stream>>>(dinv1, 1.f, NT);
  k_fill<<<NT / 256, 256, 0, stream>>>(dinv2, 1.f, NT);
  k_deg_scatter<<<NEDGE / 256, 256, 0, stream>>>(dst1, dinv1);
  k_deg_scatter<<<NEDGE / 256, 256, 0, stream>>>(dst2, dinv2);
  k_rsq<<<NT / 256, 256, 0, stream>>>(dinv1, NT);
  k_rsq<<<NT / 256, 256, 0, stream>>>(dinv2, NT);

  // -------- graph 1 conv chain
  k_mm<false><<<gElem, 256, 0, stream>>>(feat1, W1, htmp);
  k_agg_init<<<gElem, 256, 0, stream>>>(htmp, dinv1, b1, tA);
  k_agg_scatter<<<gScat, 256, 0, stream>>>(htmp, src1, dst1, dinv1, tA);
  k_mm<true><<<gElem, 256, 0, stream>>>(tA, W2, htmp);
  k_agg_init<<<gElem, 256, 0, stream>>>(htmp, dinv1, b2, tB);
  k_agg_scatter<<<gScat, 256, 0, stream>>>(htmp, src1, dst1, dinv1, tB);
  k_mm<true><<<gElem, 256, 0, stream>>>(tB, W3, htmp);
  k_agg_init<<<gElem, 256, 0, stream>>>(htmp, dinv1, b3, f13);
  k_agg_scatter<<<gScat, 256, 0, stream>>>(htmp, src1, dst1, dinv1, f13);
  k_pool_sum<<<BATCH, 128, 0, stream>>>(feat1, gfs, 0);
  k_pool_sum<<<BATCH, 128, 0, stream>>>(tA,    gfs, 128);
  k_pool_sum<<<BATCH, 128, 0, stream>>>(tB,    gfs, 256);
  k_pool_sum<<<BATCH, 128, 0, stream>>>(f13,   gfs, 384);

  // -------- graph 2 conv chain
  k_mm<false><<<gElem, 256, 0, stream>>>(feat2, W1, htmp);
  k_agg_init<<<gElem, 256, 0, stream>>>(htmp, dinv2, b1, tA);
  k_agg_scatter<<<gScat, 256, 0, stream>>>(htmp, src2, dst2, dinv2, tA);
  k_mm<true><<<gElem, 256, 0, stream>>>(tA, W2, htmp);
  k_agg_init<<<gElem, 256, 0, stream>>>(htmp, dinv2, b2, tB);
  k_agg_scatter<<<gScat, 256, 0, stream>>>(htmp, src2, dst2, dinv2, tB);
  k_mm<true><<<gElem, 256, 0, stream>>>(tB, W3, htmp);
  k_agg_init<<<gElem, 256, 0, stream>>>(htmp, dinv2, b3, f23);
  k_agg_scatter<<<gScat, 256, 0, stream>>>(htmp, src2, dst2, dinv2, f23);
  k_pool_max<<<BATCH, 128, 0, stream>>>(feat2, gfs, 512);
  k_pool_max<<<BATCH, 128, 0, stream>>>(tA,    gfs, 640);
  k_pool_max<<<BATCH, 128, 0, stream>>>(tB,    gfs, 768);
  k_pool_max<<<BATCH, 128, 0, stream>>>(f23,   gfs, 896);

  // -------- sim1
  k_mm<false><<<gElem, 256, 0, stream>>>(feat1, Aaff, htmp);   // Y = feat1 @ A
  k_affS<<<BATCH, 256, 0, stream>>>(htmp, feat2, S1);
  k_sinkhorn<<<BATCH, 256, 0, stream>>>(S1, topk);

  // -------- sim2
  k_mm<false><<<gElem, 256, 0, stream>>>(f13, Aaff, htmp);     // Y = f13 @ A
  k_affS<<<BATCH, 256, 0, stream>>>(htmp, f23, S2);
  k_sinkhorn<<<BATCH, 256, 0, stream>>>(S2, topk);

  // -------- ged
  k_mlp<<<BATCH, 64, 0, stream>>>(gfs, scW1, scb1, scW2, scb2, ged);
}

// Round 2
// 1287.370 us; speedup vs baseline: 2.0160x; 2.0160x over previous
//
#include <hip/hip_runtime.h>
#include <math.h>

#define BATCH 256
#define NNODE 128
#define NT    32768      // BATCH*NNODE
#define FDIM  128
#define NEDGE 262144
#define LBL   29
#define MAXDEG 16
#define RWD   16
#define NTF   (NT * FDIM)   // 4194304 elements per feature matrix

// ---------------------------------------------------------------- init feat
__global__ __launch_bounds__(256) void k_init_feat(
    const float* __restrict__ x, const int* __restrict__ cent,
    const float* __restrict__ rw, const float* __restrict__ demb,
    const float* __restrict__ W, const float* __restrict__ b,
    float* __restrict__ out) {
  int gid = blockIdx.x * 256 + threadIdx.x;      // NT*FDIM threads
  int row = gid >> 7, f = gid & 127;
  const float* xr = x + row * LBL;
  const float* er = demb + cent[row] * MAXDEG;
  const float* rr = rw + row * RWD;
  float acc = b[f];
#pragma unroll
  for (int k = 0; k < LBL; ++k)    acc += xr[k] * W[k * FDIM + f];
#pragma unroll
  for (int k = 0; k < MAXDEG; ++k) acc += er[k] * W[(LBL + k) * FDIM + f];
#pragma unroll
  for (int k = 0; k < RWD; ++k)    acc += rr[k] * W[(LBL + MAXDEG + k) * FDIM + f];
  out[gid] = fmaxf(acc, 0.f);
}

// ---------------------------------------------------------------- CSR build
__global__ void k_zero_i(int* __restrict__ p, int n) {
  int i = blockIdx.x * 256 + threadIdx.x;
  if (i < n) p[i] = 0;
}
__global__ void k_deg_count(const int* __restrict__ dst, int* __restrict__ degi) {
  int e = blockIdx.x * 256 + threadIdx.x;
  if (e < NEDGE) atomicAdd(&degi[dst[e]], 1);
}
__global__ void k_dinv(const int* __restrict__ degi, float* __restrict__ dinv, int n) {
  int i = blockIdx.x * 256 + threadIdx.x;
  if (i < n) dinv[i] = rsqrtf((float)(degi[i] + 1));   // +1 self loop, always >=1
}
// one block, 1024 threads: exclusive scan of degi[NT] -> ofs, cur
__global__ __launch_bounds__(1024) void k_scan(const int* __restrict__ degi,
                                               int* __restrict__ ofs,
                                               int* __restrict__ cur) {
  __shared__ int part[1024];
  int t = threadIdx.x;
  int base = t * 32;
  int loc[32]; int sum = 0;
#pragma unroll
  for (int u = 0; u < 32; ++u) { loc[u] = sum; sum += degi[base + u]; }
  part[t] = sum;
  __syncthreads();
  for (int off = 1; off < 1024; off <<= 1) {
    int v = (t >= off) ? part[t - off] : 0;
    __syncthreads();
    part[t] += v;
    __syncthreads();
  }
  int excl = (t == 0) ? 0 : part[t - 1];
#pragma unroll
  for (int u = 0; u < 32; ++u) {
    int o = excl + loc[u];
    ofs[base + u] = o; cur[base + u] = o;
  }
}
__global__ void k_csr_fill(const int* __restrict__ src, const int* __restrict__ dst,
                           int* __restrict__ cur, int* __restrict__ csr) {
  int e = blockIdx.x * 256 + threadIdx.x;
  if (e < NEDGE) {
    int pos = atomicAdd(&cur[dst[e]], 1);
    csr[pos] = src[e];
  }
}

// ---------------------------------------------------------------- dense mm (tiled)
// out (NT x 128) = relu?(A) (NT x 128) @ W (128 x 128); 32 rows/block, 4x4/thread
template <bool RELU_IN>
__global__ __launch_bounds__(256) void k_mm(const float* __restrict__ A,
                                            const float* __restrict__ W,
                                            float* __restrict__ out) {
  int t = threadIdx.x;
  int tx = t & 31, ty = t >> 5;              // tx: 4-col group, ty: 4-row group
  int r0 = blockIdx.x * 32 + ty * 4;
  float acc[4][4] = {};
  for (int k4 = 0; k4 < FDIM; k4 += 4) {
    float4 a[4], w[4];
#pragma unroll
    for (int i = 0; i < 4; ++i)
      a[i] = *reinterpret_cast<const float4*>(&A[(size_t)(r0 + i) * FDIM + k4]);
#pragma unroll
    for (int c = 0; c < 4; ++c)
      w[c] = *reinterpret_cast<const float4*>(&W[(k4 + c) * FDIM + tx * 4]);
    if (RELU_IN) {
#pragma unroll
      for (int i = 0; i < 4; ++i) {
        a[i].x = fmaxf(a[i].x, 0.f); a[i].y = fmaxf(a[i].y, 0.f);
        a[i].z = fmaxf(a[i].z, 0.f); a[i].w = fmaxf(a[i].w, 0.f);
      }
    }
#pragma unroll
    for (int i = 0; i < 4; ++i) {
      acc[i][0] += a[i].x * w[0].x; acc[i][1] += a[i].x * w[0].y;
      acc[i][2] += a[i].x * w[0].z; acc[i][3] += a[i].x * w[0].w;
      acc[i][0] += a[i].y * w[1].x; acc[i][1] += a[i].y * w[1].y;
      acc[i][2] += a[i].y * w[1].z; acc[i][3] += a[i].y * w[1].w;
      acc[i][0] += a[i].z * w[2].x; acc[i][1] += a[i].z * w[2].y;
      acc[i][2] += a[i].z * w[2].z; acc[i][3] += a[i].z * w[2].w;
      acc[i][0] += a[i].w * w[3].x; acc[i][1] += a[i].w * w[3].y;
      acc[i][2] += a[i].w * w[3].z; acc[i][3] += a[i].w * w[3].w;
    }
  }
#pragma unroll
  for (int i = 0; i < 4; ++i) {
    float4 o = make_float4(acc[i][0], acc[i][1], acc[i][2], acc[i][3]);
    *reinterpret_cast<float4*>(&out[(size_t)(r0 + i) * FDIM + tx * 4]) = o;
  }
}

// ---------------------------------------------------------------- gcn aggregate (CSR gather)
// out[d][f] = b[f] + dinv[d]*( dinv[d]*h[d][f] + sum_e dinv[s]*h[s][f] )
__global__ __launch_bounds__(256) void k_conv(
    const float* __restrict__ h, const int* __restrict__ ofs,
    const int* __restrict__ endp, const int* __restrict__ csr,
    const float* __restrict__ dinv, const float* __restrict__ b,
    float* __restrict__ out) {
  int gid = blockIdx.x * 256 + threadIdx.x;   // NT*128 threads
  int d = gid >> 7, f = gid & 127;
  float dd = dinv[d];
  float acc = dd * h[(size_t)d * FDIM + f];
  int e0 = ofs[d], e1 = endp[d];
  for (int j = e0; j < e1; ++j) {
    int s = csr[j];
    acc += dinv[s] * h[(size_t)s * FDIM + f];
  }
  out[gid] = b[f] + dd * acc;
}

// ---------------------------------------------------------------- pooling
__global__ __launch_bounds__(128) void k_pool_sum(const float* __restrict__ m,
                                                  float* __restrict__ gfs, int colofs) {
  int b = blockIdx.x, c = threadIdx.x;
  const float* base = m + (size_t)b * NNODE * FDIM + c;
  float s = 0.f;
  for (int n = 0; n < NNODE; ++n) s += base[n * FDIM];
  gfs[b * 1024 + colofs + c] = s;
}
__global__ __launch_bounds__(128) void k_pool_max(const float* __restrict__ m,
                                                  float* __restrict__ gfs, int colofs) {
  int b = blockIdx.x, c = threadIdx.x;
  const float* base = m + (size_t)b * NNODE * FDIM + c;
  float s = -INFINITY;
  for (int n = 0; n < NNODE; ++n) s = fmaxf(s, base[n * FDIM]);
  gfs[b * 1024 + colofs + c] = s;
}

// ---------------------------------------------------------------- affinity S[b] = Y[b] @ X[b]^T
// grid = BATCH*2; block handles 64 i-rows x 128 j-cols; thread tile 4x8
__global__ __launch_bounds__(256) void k_affS(const float* __restrict__ Y,
                                              const float* __restrict__ X,
                                              float* __restrict__ S) {
  __shared__ float Ys[32][68];    // k-major, padded
  __shared__ float Xs[32][132];
  int t = threadIdx.x;
  int b = blockIdx.x >> 1;
  int ib = (blockIdx.x & 1) * 64;
  const float* Yb = Y + (size_t)b * NNODE * FDIM + (size_t)ib * FDIM;
  const float* Xb = X + (size_t)b * NNODE * FDIM;
  float* Sb = S + (size_t)b * NNODE * NNODE;
  int i0 = (t >> 4) * 4;          // 0..60
  int j0 = (t & 15) * 8;          // 0..120
  float acc[4][8] = {};
  for (int kc = 0; kc < FDIM; kc += 32) {
    __syncthreads();
    // stage Y tile: 64 rows x 32 k, transposed
#pragma unroll
    for (int q = 0; q < 2; ++q) {
      int l = t + 256 * q;
      int row = l >> 3, kq = (l & 7) << 2;
      float4 y = *reinterpret_cast<const float4*>(&Yb[(size_t)row * FDIM + kc + kq]);
      Ys[kq + 0][row] = y.x; Ys[kq + 1][row] = y.y;
      Ys[kq + 2][row] = y.z; Ys[kq + 3][row] = y.w;
    }
    // stage X tile: 128 rows x 32 k, transposed
#pragma unroll
    for (int q = 0; q < 4; ++q) {
      int l = t + 256 * q;
      int row = l >> 3, kq = (l & 7) << 2;
      float4 xv = *reinterpret_cast<const float4*>(&Xb[(size_t)row * FDIM + kc + kq]);
      Xs[kq + 0][row] = xv.x; Xs[kq + 1][row] = xv.y;
      Xs[kq + 2][row] = xv.z; Xs[kq + 3][row] = xv.w;
    }
    __syncthreads();
#pragma unroll
    for (int kk = 0; kk < 32; ++kk) {
      float4 y4 = *reinterpret_cast<const float4*>(&Ys[kk][i0]);
      float4 xa = *reinterpret_cast<const float4*>(&Xs[kk][j0]);
      float4 xb = *reinterpret_cast<const float4*>(&Xs[kk][j0 + 4]);
      float yv[4] = {y4.x, y4.y, y4.z, y4.w};
      float xv[8] = {xa.x, xa.y, xa.z, xa.w, xb.x, xb.y, xb.z, xb.w};
#pragma unroll
      for (int ii = 0; ii < 4; ++ii)
#pragma unroll
        for (int jj = 0; jj < 8; ++jj)
          acc[ii][jj] += yv[ii] * xv[jj];
    }
  }
#pragma unroll
  for (int ii = 0; ii < 4; ++ii) {
    float4 o0 = make_float4(acc[ii][0], acc[ii][1], acc[ii][2], acc[ii][3]);
    float4 o1 = make_float4(acc[ii][4], acc[ii][5], acc[ii][6], acc[ii][7]);
    float* dst = &Sb[(size_t)(ib + i0 + ii) * NNODE + j0];
    *reinterpret_cast<float4*>(dst) = o0;
    *reinterpret_cast<float4*>(dst + 4) = o1;
  }
}

// ---------------------------------------------------------------- sinkhorn soft-topk (in place)
__global__ __launch_bounds__(256) void k_sinkhorn(float* __restrict__ S,
                                                  const int* __restrict__ topk) {
  const int L = NNODE * NNODE;           // 16384
  int b = blockIdx.x, t = threadIdx.x;
  int wave = t >> 6, lane = t & 63;
  float* x = S + (size_t)b * L;

  __shared__ float red[8];
  __shared__ float bc[2];
  __shared__ float rm[8], rs[8];

  float xv[64];
#pragma unroll
  for (int u = 0; u < 64; ++u) xv[u] = x[t + 256 * u];

  float mn = xv[0], mx = xv[0];
#pragma unroll
  for (int u = 1; u < 64; ++u) { mn = fminf(mn, xv[u]); mx = fmaxf(mx, xv[u]); }
  for (int off = 32; off > 0; off >>= 1) {
    mn = fminf(mn, __shfl_down(mn, off));
    mx = fmaxf(mx, __shfl_down(mx, off));
  }
  if (lane == 0) { red[wave] = mn; red[4 + wave] = mx; }
  __syncthreads();
  if (t == 0) {
    float a = fminf(fminf(red[0], red[1]), fminf(red[2], red[3]));
    float c = fmaxf(fmaxf(red[4], red[5]), fmaxf(red[6], red[7]));
    bc[0] = a - 1.f; bc[1] = c + 1.f;
  }
  __syncthreads();
  float a_lo = bc[0], a_hi = bc[1];

  float kk = 0.5f * (float)topk[0];
  const float log_mu = -logf((float)L);
  float log_nu0 = logf(((float)L - kk) / (float)L);
  float log_nu1 = logf(kk / (float)L);

  float g0 = 0.f, g1 = 0.f, gp0 = 0.f, gp1 = 0.f;
  for (int it = 0; it < 6; ++it) {
    gp0 = g0; gp1 = g1;
    float m0 = -INFINITY, s0 = 0.f, m1 = -INFINITY, s1 = 0.f;
#pragma unroll
    for (int u = 0; u < 64; ++u) {
      float xi = xv[u];
      float k0 = a_lo - xi;
      float k1 = xi - a_hi;
      float t0 = k0 + g0, t1 = k1 + g1;
      float mm = fmaxf(t0, t1);
      float f = log_mu - (mm + __logf(__expf(t0 - mm) + __expf(t1 - mm)));
      float e0 = k0 + f, e1 = k1 + f;
      if (e0 > m0) { s0 = s0 * __expf(m0 - e0) + 1.f; m0 = e0; } else s0 += __expf(e0 - m0);
      if (e1 > m1) { s1 = s1 * __expf(m1 - e1) + 1.f; m1 = e1; } else s1 += __expf(e1 - m1);
    }
    for (int off = 32; off > 0; off >>= 1) {
      float om = __shfl_down(m0, off), os = __shfl_down(s0, off);
      float M = fmaxf(m0, om);
      s0 = s0 * __expf(m0 - M) + os * __expf(om - M); m0 = M;
      om = __shfl_down(m1, off); os = __shfl_down(s1, off);
      M = fmaxf(m1, om);
      s1 = s1 * __expf(m1 - M) + os * __expf(om - M); m1 = M;
    }
    if (lane == 0) { rm[wave] = m0; rs[wave] = s0; rm[4 + wave] = m1; rs[4 + wave] = s1; }
    __syncthreads();
    if (t == 0) {
      float M0 = fmaxf(fmaxf(rm[0], rm[1]), fmaxf(rm[2], rm[3]));
      float S0 = rs[0] * __expf(rm[0] - M0) + rs[1] * __expf(rm[1] - M0) +
                 rs[2] * __expf(rm[2] - M0) + rs[3] * __expf(rm[3] - M0);
      float M1 = fmaxf(fmaxf(rm[4], rm[5]), fmaxf(rm[6], rm[7]));
      float S1 = rs[4] * __expf(rm[4] - M1) + rs[5] * __expf(rm[5] - M1) +
                 rs[6] * __expf(rm[6] - M1) + rs[7] * __expf(rm[7] - M1);
      bc[0] = log_nu0 - (M0 + __logf(S0));
      bc[1] = log_nu1 - (M1 + __logf(S1));
    }
    __syncthreads();
    g0 = bc[0]; g1 = bc[1];
    __syncthreads();
  }
  const float Lf = (float)L;
#pragma unroll
  for (int u = 0; u < 64; ++u) {
    float xi = xv[u];
    float k0 = a_lo - xi, k1 = xi - a_hi;
    float t0 = k0 + gp0, t1 = k1 + gp1;
    float mm = fmaxf(t0, t1);
    float f = log_mu - (mm + __logf(__expf(t0 - mm) + __expf(t1 - mm)));
    x[t + 256 * u] = __expf(k1 + f + g1) * Lf;
  }
}

// ---------------------------------------------------------------- scoring MLP
__global__ __launch_bounds__(256) void k_mlp(const float* __restrict__ gfs,
                                             const float* __restrict__ W1,
                                             const float* __restrict__ b1,
                                             const float* __restrict__ W2,
                                             const float* __restrict__ b2,
                                             float* __restrict__ ged) {
  __shared__ float part[256];
  int b = blockIdx.x, t = threadIdx.x, j = t & 63, p = t >> 6;
  const float* s = gfs + b * 1024;
  float acc = 0.f;
  for (int k = p * 256; k < p * 256 + 256; ++k) acc += s[k] * W1[k * 64 + j];
  part[t] = acc;
  __syncthreads();
  if (t < 64) {
    float h = b1[j] + part[j] + part[j + 64] + part[j + 128] + part[j + 192];
    h = fmaxf(h, 0.f);
    float v = h * W2[j];
    for (int off = 32; off > 0; off >>= 1) v += __shfl_down(v, off);
    if (j == 0) ged[b] = 1.f / (1.f + __expf(-(v + b2[0])));
  }
}

// ================================================================ launch
extern "C" void kernel_launch(void* const* d_in, const int* in_sizes, int n_in,
                              void* d_out, int out_size, void* d_ws, size_t ws_size,
                              hipStream_t stream) {
  (void)in_sizes; (void)n_in; (void)out_size; (void)ws_size;
  const float* x1    = (const float*)d_in[0];
  const int*   cent1 = (const int*)  d_in[1];
  const float* rw1   = (const float*)d_in[2];
  const int*   src1  = (const int*)  d_in[3];
  const int*   dst1  = (const int*)  d_in[4];
  const float* x2    = (const float*)d_in[5];
  const int*   cent2 = (const int*)  d_in[6];
  const float* rw2   = (const float*)d_in[7];
  const int*   src2  = (const int*)  d_in[8];
  const int*   dst2  = (const int*)  d_in[9];
  const float* demb  = (const float*)d_in[10];
  const float* initW = (const float*)d_in[11];
  const float* initb = (const float*)d_in[12];
  const float* W1    = (const float*)d_in[13];
  const float* b1    = (const float*)d_in[14];
  const float* W2    = (const float*)d_in[15];
  const float* b2    = (const float*)d_in[16];
  const float* W3    = (const float*)d_in[17];
  const float* b3    = (const float*)d_in[18];
  const float* Aaff  = (const float*)d_in[19];
  const float* scW1  = (const float*)d_in[20];
  const float* scb1  = (const float*)d_in[21];
  const float* scW2  = (const float*)d_in[22];
  const float* scb2  = (const float*)d_in[23];
  const int*   topk  = (const int*)  d_in[24];

  float* ws    = (float*)d_ws;
  float* feat1 = ws;
  float* feat2 = ws + (size_t)1 * NTF;
  float* tA    = ws + (size_t)2 * NTF;
  float* tB    = ws + (size_t)3 * NTF;
  float* f13   = ws + (size_t)4 * NTF;
  float* f23   = ws + (size_t)5 * NTF;
  float* htmp  = ws + (size_t)6 * NTF;   // also reused as Y
  float* dinv1 = ws + (size_t)7 * NTF;
  float* dinv2 = dinv1 + NT;
  float* gfs   = dinv2 + NT;             // 256*1024

  float* ged = (float*)d_out;
  float* S1  = ged + BATCH;
  float* S2  = S1 + (size_t)BATCH * NNODE * NNODE;

  // int scratch lives in S1's output region (only written by affS AFTER convs)
  int* degi1 = (int*)S1;
  int* ofs1  = degi1 + NT;
  int* cur1  = ofs1 + NT;
  int* csr1  = cur1 + NT;
  int* degi2 = csr1 + NEDGE;
  int* ofs2  = degi2 + NT;
  int* cur2  = ofs2 + NT;
  int* csr2  = cur2 + NT;

  const int gElem = NT * FDIM / 256;     // 16384 blocks
  const int gMM   = NT / 32;             // 1024 blocks
  const int gE    = NEDGE / 256;
  const int gN    = NT / 256;

  // init features
  k_init_feat<<<gElem, 256, 0, stream>>>(x1, cent1, rw1, demb, initW, initb, feat1);
  k_init_feat<<<gElem, 256, 0, stream>>>(x2, cent2, rw2, demb, initW, initb, feat2);

  // CSR + degree norms, graph 1 & 2
  k_zero_i<<<gN, 256, 0, stream>>>(degi1, NT);
  k_zero_i<<<gN, 256, 0, stream>>>(degi2, NT);
  k_deg_count<<<gE, 256, 0, stream>>>(dst1, degi1);
  k_deg_count<<<gE, 256, 0, stream>>>(dst2, degi2);
  k_dinv<<<gN, 256, 0, stream>>>(degi1, dinv1, NT);
  k_dinv<<<gN, 256, 0, stream>>>(degi2, dinv2, NT);
  k_scan<<<1, 1024, 0, stream>>>(degi1, ofs1, cur1);
  k_scan<<<1, 1024, 0, stream>>>(degi2, ofs2, cur2);
  k_csr_fill<<<gE, 256, 0, stream>>>(src1, dst1, cur1, csr1);
  k_csr_fill<<<gE, 256, 0, stream>>>(src2, dst2, cur2, csr2);
  // after fill, cur[d] == end of bucket d

  // -------- graph 1 conv chain
  k_mm<false><<<gMM, 256, 0, stream>>>(feat1, W1, htmp);
  k_conv<<<gElem, 256, 0, stream>>>(htmp, ofs1, cur1, csr1, dinv1, b1, tA);
  k_mm<true><<<gMM, 256, 0, stream>>>(tA, W2, htmp);
  k_conv<<<gElem, 256, 0, stream>>>(htmp, ofs1, cur1, csr1, dinv1, b2, tB);
  k_mm<true><<<gMM, 256, 0, stream>>>(tB, W3, htmp);
  k_conv<<<gElem, 256, 0, stream>>>(htmp, ofs1, cur1, csr1, dinv1, b3, f13);
  k_pool_sum<<<BATCH, 128, 0, stream>>>(feat1, gfs, 0);
  k_pool_sum<<<BATCH, 128, 0, stream>>>(tA,    gfs, 128);
  k_pool_sum<<<BATCH, 128, 0, stream>>>(tB,    gfs, 256);
  k_pool_sum<<<BATCH, 128, 0, stream>>>(f13,   gfs, 384);

  // -------- graph 2 conv chain
  k_mm<false><<<gMM, 256, 0, stream>>>(feat2, W1, htmp);
  k_conv<<<gElem, 256, 0, stream>>>(htmp, ofs2, cur2, csr2, dinv2, b1, tA);
  k_mm<true><<<gMM, 256, 0, stream>>>(tA, W2, htmp);
  k_conv<<<gElem, 256, 0, stream>>>(htmp, ofs2, cur2, csr2, dinv2, b2, tB);
  k_mm<true><<<gMM, 256, 0, stream>>>(tB, W3, htmp);
  k_conv<<<gElem, 256, 0, stream>>>(htmp, ofs2, cur2, csr2, dinv2, b3, f23);
  k_pool_max<<<BATCH, 128, 0, stream>>>(feat2, gfs, 512);
  k_pool_max<<<BATCH, 128, 0, stream>>>(tA,    gfs, 640);
  k_pool_max<<<BATCH, 128, 0, stream>>>(tB,    gfs, 768);
  k_pool_max<<<BATCH, 128, 0, stream>>>(f23,   gfs, 896);

  // -------- sim1 (CSR scratch in S1 region no longer needed)
  k_mm<false><<<gMM, 256, 0, stream>>>(feat1, Aaff, htmp);   // Y = feat1 @ A
  k_affS<<<BATCH * 2, 256, 0, stream>>>(htmp, feat2, S1);
  k_sinkhorn<<<BATCH, 256, 0, stream>>>(S1, topk);

  // -------- sim2
  k_mm<false><<<gMM, 256, 0, stream>>>(f13, Aaff, htmp);     // Y = f13 @ A
  k_affS<<<BATCH * 2, 256, 0, stream>>>(htmp, f23, S2);
  k_sinkhorn<<<BATCH, 256, 0, stream>>>(S2, topk);

  // -------- ged
  k_mlp<<<BATCH, 256, 0, stream>>>(gfs, scW1, scb1, scW2, scb2, ged);
}

// Round 3
// 1058.351 us; speedup vs baseline: 2.4522x; 1.2164x over previous
//
#include <hip/hip_runtime.h>
#include <math.h>

#define BATCH 256
#define NNODE 128
#define NT    32768      // BATCH*NNODE
#define FDIM  128
#define NEDGE 262144
#define LBL   29
#define MAXDEG 16
#define RWD   16
#define NTF   (NT * FDIM)   // 4194304 elements per feature matrix

// ---------------------------------------------------------------- init feat
__global__ __launch_bounds__(256) void k_init_feat(
    const float* __restrict__ x, const int* __restrict__ cent,
    const float* __restrict__ rw, const float* __restrict__ demb,
    const float* __restrict__ W, const float* __restrict__ b,
    float* __restrict__ out) {
  int gid = blockIdx.x * 256 + threadIdx.x;      // NT*FDIM threads
  int row = gid >> 7, f = gid & 127;
  const float* xr = x + row * LBL;
  const float* er = demb + cent[row] * MAXDEG;
  const float* rr = rw + row * RWD;
  float acc = b[f];
#pragma unroll
  for (int k = 0; k < LBL; ++k)    acc += xr[k] * W[k * FDIM + f];
#pragma unroll
  for (int k = 0; k < MAXDEG; ++k) acc += er[k] * W[(LBL + k) * FDIM + f];
#pragma unroll
  for (int k = 0; k < RWD; ++k)    acc += rr[k] * W[(LBL + MAXDEG + k) * FDIM + f];
  out[gid] = fmaxf(acc, 0.f);
}

// ---------------------------------------------------------------- CSR build
__global__ void k_zero_i(int* __restrict__ p, int n) {
  int i = blockIdx.x * 256 + threadIdx.x;
  if (i < n) p[i] = 0;
}
__global__ void k_deg_count(const int* __restrict__ dst, int* __restrict__ degi) {
  int e = blockIdx.x * 256 + threadIdx.x;
  if (e < NEDGE) atomicAdd(&degi[dst[e]], 1);
}
__global__ void k_dinv(const int* __restrict__ degi, float* __restrict__ dinv, int n) {
  int i = blockIdx.x * 256 + threadIdx.x;
  if (i < n) dinv[i] = rsqrtf((float)(degi[i] + 1));   // +1 self loop
}
__global__ __launch_bounds__(1024) void k_scan(const int* __restrict__ degi,
                                               int* __restrict__ ofs,
                                               int* __restrict__ cur) {
  __shared__ int part[1024];
  int t = threadIdx.x;
  int base = t * 32;
  int loc[32]; int sum = 0;
#pragma unroll
  for (int u = 0; u < 32; ++u) { loc[u] = sum; sum += degi[base + u]; }
  part[t] = sum;
  __syncthreads();
  for (int off = 1; off < 1024; off <<= 1) {
    int v = (t >= off) ? part[t - off] : 0;
    __syncthreads();
    part[t] += v;
    __syncthreads();
  }
  int excl = (t == 0) ? 0 : part[t - 1];
#pragma unroll
  for (int u = 0; u < 32; ++u) {
    int o = excl + loc[u];
    ofs[base + u] = o; cur[base + u] = o;
  }
}
__global__ void k_csr_fill(const int* __restrict__ src, const int* __restrict__ dst,
                           int* __restrict__ cur, int* __restrict__ csr) {
  int e = blockIdx.x * 256 + threadIdx.x;
  if (e < NEDGE) {
    int pos = atomicAdd(&cur[dst[e]], 1);
    csr[pos] = src[e];
  }
}

// ---------------------------------------------------------------- dense mm (LDS-staged)
// out (NT x 128) = relu?(A) (NT x 128) @ W (128 x 128); 32 rows/block, 4x4/thread
template <bool RELU_IN>
__global__ __launch_bounds__(256) void k_mm(const float* __restrict__ A,
                                            const float* __restrict__ W,
                                            float* __restrict__ out) {
  __shared__ float As[32][132];   // padded; 132%4==0 so float4 stores stay aligned
  __shared__ float Ws[32][128];
  int t = threadIdx.x;
  int tx = t & 31, ty = t >> 5;
  int r0 = blockIdx.x * 32;
  // stage A tile (apply relu here, once)
#pragma unroll
  for (int q = 0; q < 4; ++q) {
    int l = t + 256 * q;
    int row = l >> 5, c4 = (l & 31) << 2;
    float4 a = *reinterpret_cast<const float4*>(&A[(size_t)(r0 + row) * FDIM + c4]);
    if (RELU_IN) {
      a.x = fmaxf(a.x, 0.f); a.y = fmaxf(a.y, 0.f);
      a.z = fmaxf(a.z, 0.f); a.w = fmaxf(a.w, 0.f);
    }
    *reinterpret_cast<float4*>(&As[row][c4]) = a;
  }
  float acc[4][4] = {};
  for (int kc = 0; kc < FDIM; kc += 32) {
    __syncthreads();
#pragma unroll
    for (int q = 0; q < 4; ++q) {
      int l = t + 256 * q;
      int row = l >> 5, c4 = (l & 31) << 2;
      *reinterpret_cast<float4*>(&Ws[row][c4]) =
          *reinterpret_cast<const float4*>(&W[(size_t)(kc + row) * FDIM + c4]);
    }
    __syncthreads();
#pragma unroll
    for (int k = 0; k < 32; ++k) {
      float4 w = *reinterpret_cast<const float4*>(&Ws[k][tx * 4]);
      float a0 = As[ty * 4 + 0][kc + k];
      float a1 = As[ty * 4 + 1][kc + k];
      float a2 = As[ty * 4 + 2][kc + k];
      float a3 = As[ty * 4 + 3][kc + k];
      acc[0][0] += a0 * w.x; acc[0][1] += a0 * w.y; acc[0][2] += a0 * w.z; acc[0][3] += a0 * w.w;
      acc[1][0] += a1 * w.x; acc[1][1] += a1 * w.y; acc[1][2] += a1 * w.z; acc[1][3] += a1 * w.w;
      acc[2][0] += a2 * w.x; acc[2][1] += a2 * w.y; acc[2][2] += a2 * w.z; acc[2][3] += a2 * w.w;
      acc[3][0] += a3 * w.x; acc[3][1] += a3 * w.y; acc[3][2] += a3 * w.z; acc[3][3] += a3 * w.w;
    }
  }
#pragma unroll
  for (int i = 0; i < 4; ++i) {
    float4 o = make_float4(acc[i][0], acc[i][1], acc[i][2], acc[i][3]);
    *reinterpret_cast<float4*>(&out[(size_t)(r0 + ty * 4 + i) * FDIM + tx * 4]) = o;
  }
}

// ---------------------------------------------------------------- gcn aggregate (CSR gather)
__global__ __launch_bounds__(256) void k_conv(
    const float* __restrict__ h, const int* __restrict__ ofs,
    const int* __restrict__ endp, const int* __restrict__ csr,
    const float* __restrict__ dinv, const float* __restrict__ b,
    float* __restrict__ out) {
  int gid = blockIdx.x * 256 + threadIdx.x;   // NT*128 threads
  int d = gid >> 7, f = gid & 127;
  float dd = dinv[d];
  float acc = dd * h[(size_t)d * FDIM + f];
  int e0 = ofs[d], e1 = endp[d];
  for (int j = e0; j < e1; ++j) {
    int s = csr[j];
    acc += dinv[s] * h[(size_t)s * FDIM + f];
  }
  out[gid] = b[f] + dd * acc;
}

// ---------------------------------------------------------------- fused pooling
__global__ __launch_bounds__(256) void k_pool_sum4(
    const float* __restrict__ m0, const float* __restrict__ m1,
    const float* __restrict__ m2, const float* __restrict__ m3,
    float* __restrict__ gfs) {
  __shared__ float part[256];
  int b = blockIdx.x >> 2, mi = blockIdx.x & 3;
  const float* m = (mi == 0) ? m0 : (mi == 1) ? m1 : (mi == 2) ? m2 : m3;
  int t = threadIdx.x;
  int c = t & 127, half = t >> 7;
  const float* base = m + (size_t)b * NNODE * FDIM + c;
  float s = 0.f;
  for (int n = half * 64; n < half * 64 + 64; ++n) s += base[n * FDIM];
  part[t] = s;
  __syncthreads();
  if (t < 128) gfs[b * 1024 + mi * 128 + t] = part[t] + part[t + 128];
}
__global__ __launch_bounds__(256) void k_pool_max4(
    const float* __restrict__ m0, const float* __restrict__ m1,
    const float* __restrict__ m2, const float* __restrict__ m3,
    float* __restrict__ gfs) {
  __shared__ float part[256];
  int b = blockIdx.x >> 2, mi = blockIdx.x & 3;
  const float* m = (mi == 0) ? m0 : (mi == 1) ? m1 : (mi == 2) ? m2 : m3;
  int t = threadIdx.x;
  int c = t & 127, half = t >> 7;
  const float* base = m + (size_t)b * NNODE * FDIM + c;
  float s = -INFINITY;
  for (int n = half * 64; n < half * 64 + 64; ++n) s = fmaxf(s, base[n * FDIM]);
  part[t] = s;
  __syncthreads();
  if (t < 128) gfs[b * 1024 + 512 + mi * 128 + t] = fmaxf(part[t], part[t + 128]);
}

// ---------------------------------------------------------------- affinity S[b] = Y[b] @ X[b]^T
__global__ __launch_bounds__(256) void k_affS(const float* __restrict__ Y,
                                              const float* __restrict__ X,
                                              float* __restrict__ S) {
  __shared__ float Ys[32][68];    // k-major, padded
  __shared__ float Xs[32][132];
  int t = threadIdx.x;
  int b = blockIdx.x >> 1;
  int ib = (blockIdx.x & 1) * 64;
  const float* Yb = Y + (size_t)b * NNODE * FDIM + (size_t)ib * FDIM;
  const float* Xb = X + (size_t)b * NNODE * FDIM;
  float* Sb = S + (size_t)b * NNODE * NNODE;
  int i0 = (t >> 4) * 4;          // 0..60
  int j0 = (t & 15) * 8;          // 0..120
  float acc[4][8] = {};
  for (int kc = 0; kc < FDIM; kc += 32) {
    __syncthreads();
#pragma unroll
    for (int q = 0; q < 2; ++q) {
      int l = t + 256 * q;
      int row = l >> 3, kq = (l & 7) << 2;
      float4 y = *reinterpret_cast<const float4*>(&Yb[(size_t)row * FDIM + kc + kq]);
      Ys[kq + 0][row] = y.x; Ys[kq + 1][row] = y.y;
      Ys[kq + 2][row] = y.z; Ys[kq + 3][row] = y.w;
    }
#pragma unroll
    for (int q = 0; q < 4; ++q) {
      int l = t + 256 * q;
      int row = l >> 3, kq = (l & 7) << 2;
      float4 xv = *reinterpret_cast<const float4*>(&Xb[(size_t)row * FDIM + kc + kq]);
      Xs[kq + 0][row] = xv.x; Xs[kq + 1][row] = xv.y;
      Xs[kq + 2][row] = xv.z; Xs[kq + 3][row] = xv.w;
    }
    __syncthreads();
#pragma unroll
    for (int kk = 0; kk < 32; ++kk) {
      float4 y4 = *reinterpret_cast<const float4*>(&Ys[kk][i0]);
      float4 xa = *reinterpret_cast<const float4*>(&Xs[kk][j0]);
      float4 xb = *reinterpret_cast<const float4*>(&Xs[kk][j0 + 4]);
      float yv[4] = {y4.x, y4.y, y4.z, y4.w};
      float xv[8] = {xa.x, xa.y, xa.z, xa.w, xb.x, xb.y, xb.z, xb.w};
#pragma unroll
      for (int ii = 0; ii < 4; ++ii)
#pragma unroll
        for (int jj = 0; jj < 8; ++jj)
          acc[ii][jj] += yv[ii] * xv[jj];
    }
  }
#pragma unroll
  for (int ii = 0; ii < 4; ++ii) {
    float4 o0 = make_float4(acc[ii][0], acc[ii][1], acc[ii][2], acc[ii][3]);
    float4 o1 = make_float4(acc[ii][4], acc[ii][5], acc[ii][6], acc[ii][7]);
    float* dst = &Sb[(size_t)(ib + i0 + ii) * NNODE + j0];
    *reinterpret_cast<float4*>(dst) = o0;
    *reinterpret_cast<float4*>(dst + 4) = o1;
  }
}

// ---------------------------------------------------------------- sinkhorn soft-topk (in place)
// 1024 threads, 16 elems/thread; store-then-reduce LSE (no serial exp chains)
__global__ __launch_bounds__(1024) void k_sinkhorn(float* __restrict__ S,
                                                   const int* __restrict__ topk) {
  const int L = NNODE * NNODE;           // 16384
  int b = blockIdx.x, t = threadIdx.x;
  int wave = t >> 6, lane = t & 63;
  float* x = S + (size_t)b * L;

  __shared__ float rA[16], rB[16], rC[16], rD[16];
  __shared__ float bc[2];

  float xv[16];
#pragma unroll
  for (int u = 0; u < 16; ++u) xv[u] = x[t + 1024 * u];

  // min / max of scores
  {
    float mn = xv[0], mx = xv[0];
#pragma unroll
    for (int u = 1; u < 16; ++u) { mn = fminf(mn, xv[u]); mx = fmaxf(mx, xv[u]); }
    for (int off = 32; off; off >>= 1) {
      mn = fminf(mn, __shfl_down(mn, off));
      mx = fmaxf(mx, __shfl_down(mx, off));
    }
    if (lane == 0) { rA[wave] = mn; rB[wave] = mx; }
    __syncthreads();
    if (t < 16) {
      mn = rA[t]; mx = rB[t];
      for (int off = 8; off; off >>= 1) {
        mn = fminf(mn, __shfl_down(mn, off));
        mx = fmaxf(mx, __shfl_down(mx, off));
      }
      if (t == 0) { bc[0] = mn - 1.f; bc[1] = mx + 1.f; }
    }
    __syncthreads();
  }
  float a_lo = bc[0], a_hi = bc[1];

  float kk = 0.5f * (float)topk[0];
  const float log_mu = -logf((float)L);
  float log_nu0 = logf(((float)L - kk) / (float)L);
  float log_nu1 = logf(kk / (float)L);

  float g0 = 0.f, g1 = 0.f, gp0 = 0.f, gp1 = 0.f;
  for (int it = 0; it < 6; ++it) {
    gp0 = g0; gp1 = g1;
    float e0[16], e1[16];
#pragma unroll
    for (int u = 0; u < 16; ++u) {
      float k0 = a_lo - xv[u], k1 = xv[u] - a_hi;
      float t0 = k0 + g0, t1 = k1 + g1;
      float mm = fmaxf(t0, t1);
      float f = log_mu - mm - log1pf(__expf(-fabsf(t0 - t1)));
      e0[u] = k0 + f; e1[u] = k1 + f;
    }
    float m0 = e0[0], m1 = e1[0];
#pragma unroll
    for (int u = 1; u < 16; ++u) { m0 = fmaxf(m0, e0[u]); m1 = fmaxf(m1, e1[u]); }
    float s0 = 0.f, s1 = 0.f;
#pragma unroll
    for (int u = 0; u < 16; ++u) {
      s0 += __expf(e0[u] - m0);
      s1 += __expf(e1[u] - m1);
    }
    for (int off = 32; off; off >>= 1) {
      float om = __shfl_down(m0, off), os = __shfl_down(s0, off);
      float M = fmaxf(m0, om);
      s0 = s0 * __expf(m0 - M) + os * __expf(om - M); m0 = M;
      om = __shfl_down(m1, off); os = __shfl_down(s1, off);
      M = fmaxf(m1, om);
      s1 = s1 * __expf(m1 - M) + os * __expf(om - M); m1 = M;
    }
    if (lane == 0) { rA[wave] = m0; rB[wave] = s0; rC[wave] = m1; rD[wave] = s1; }
    __syncthreads();
    if (t < 16) {
      m0 = rA[t]; s0 = rB[t]; m1 = rC[t]; s1 = rD[t];
      for (int off = 8; off; off >>= 1) {
        float om = __shfl_down(m0, off), os = __shfl_down(s0, off);
        float M = fmaxf(m0, om);
        s0 = s0 * __expf(m0 - M) + os * __expf(om - M); m0 = M;
        om = __shfl_down(m1, off); os = __shfl_down(s1, off);
        M = fmaxf(m1, om);
        s1 = s1 * __expf(m1 - M) + os * __expf(om - M); m1 = M;
      }
      if (t == 0) {
        bc[0] = log_nu0 - (m0 + __logf(s0));
        bc[1] = log_nu1 - (m1 + __logf(s1));
      }
    }
    __syncthreads();
    g0 = bc[0]; g1 = bc[1];
  }

  // prob = exp(logK1 + f(g_prev) + g1_final) * L
  const float Lf = (float)L;
#pragma unroll
  for (int u = 0; u < 16; ++u) {
    float k0 = a_lo - xv[u], k1 = xv[u] - a_hi;
    float t0 = k0 + gp0, t1 = k1 + gp1;
    float mm = fmaxf(t0, t1);
    float f = log_mu - mm - log1pf(__expf(-fabsf(t0 - t1)));
    x[t + 1024 * u] = __expf(k1 + f + g1) * Lf;
  }
}

// ---------------------------------------------------------------- scoring MLP
__global__ __launch_bounds__(256) void k_mlp(const float* __restrict__ gfs,
                                             const float* __restrict__ W1,
                                             const float* __restrict__ b1,
                                             const float* __restrict__ W2,
                                             const float* __restrict__ b2,
                                             float* __restrict__ ged) {
  __shared__ float sm[1024];
  int b = blockIdx.x, t = threadIdx.x;
  const float* s = gfs + b * 1024;
#pragma unroll
  for (int q = 0; q < 4; ++q) sm[t + 256 * q] = s[t + 256 * q];
  __syncthreads();
  int j4 = (t & 15) * 4, kp = t >> 4;       // 16 j-quads x 16 k-partitions
  float4 acc = make_float4(0.f, 0.f, 0.f, 0.f);
#pragma unroll 8
  for (int k = 0; k < 64; ++k) {
    float4 w = *reinterpret_cast<const float4*>(&W1[(size_t)(kp * 64 + k) * 64 + j4]);
    float sv = sm[kp * 64 + k];
    acc.x += sv * w.x; acc.y += sv * w.y; acc.z += sv * w.z; acc.w += sv * w.w;
  }
  __syncthreads();
  *reinterpret_cast<float4*>(&sm[kp * 64 + j4]) = acc;   // reuse sm as part[16][64]
  __syncthreads();
  if (t < 64) {
    float h = b1[t];
#pragma unroll
    for (int kp2 = 0; kp2 < 16; ++kp2) h += sm[kp2 * 64 + t];
    h = fmaxf(h, 0.f);
    float v = h * W2[t];
    for (int off = 32; off; off >>= 1) v += __shfl_down(v, off);
    if (t == 0) ged[b] = 1.f / (1.f + __expf(-(v + b2[0])));
  }
}

// ================================================================ launch
extern "C" void kernel_launch(void* const* d_in, const int* in_sizes, int n_in,
                              void* d_out, int out_size, void* d_ws, size_t ws_size,
                              hipStream_t stream) {
  (void)in_sizes; (void)n_in; (void)out_size; (void)ws_size;
  const float* x1    = (const float*)d_in[0];
  const int*   cent1 = (const int*)  d_in[1];
  const float* rw1   = (const float*)d_in[2];
  const int*   src1  = (const int*)  d_in[3];
  const int*   dst1  = (const int*)  d_in[4];
  const float* x2    = (const float*)d_in[5];
  const int*   cent2 = (const int*)  d_in[6];
  const float* rw2   = (const float*)d_in[7];
  const int*   src2  = (const int*)  d_in[8];
  const int*   dst2  = (const int*)  d_in[9];
  const float* demb  = (const float*)d_in[10];
  const float* initW = (const float*)d_in[11];
  const float* initb = (const float*)d_in[12];
  const float* W1    = (const float*)d_in[13];
  const float* b1    = (const float*)d_in[14];
  const float* W2    = (const float*)d_in[15];
  const float* b2    = (const float*)d_in[16];
  const float* W3    = (const float*)d_in[17];
  const float* b3    = (const float*)d_in[18];
  const float* Aaff  = (const float*)d_in[19];
  const float* scW1  = (const float*)d_in[20];
  const float* scb1  = (const float*)d_in[21];
  const float* scW2  = (const float*)d_in[22];
  const float* scb2  = (const float*)d_in[23];
  const int*   topk  = (const int*)  d_in[24];

  float* ws    = (float*)d_ws;
  float* feat1 = ws;
  float* feat2 = ws + (size_t)1 * NTF;
  float* tA    = ws + (size_t)2 * NTF;
  float* tB    = ws + (size_t)3 * NTF;
  float* f13   = ws + (size_t)4 * NTF;
  float* f23   = ws + (size_t)5 * NTF;
  float* htmp  = ws + (size_t)6 * NTF;   // also reused as Y
  float* dinv1 = ws + (size_t)7 * NTF;
  float* dinv2 = dinv1 + NT;
  float* gfs   = dinv2 + NT;             // 256*1024

  float* ged = (float*)d_out;
  float* S1  = ged + BATCH;
  float* S2  = S1 + (size_t)BATCH * NNODE * NNODE;

  // int scratch lives in S1's output region (only written by affS AFTER convs)
  int* degi1 = (int*)S1;
  int* ofs1  = degi1 + NT;
  int* cur1  = ofs1 + NT;
  int* csr1  = cur1 + NT;
  int* degi2 = csr1 + NEDGE;
  int* ofs2  = degi2 + NT;
  int* cur2  = ofs2 + NT;
  int* csr2  = cur2 + NT;

  const int gElem = NT * FDIM / 256;     // 16384 blocks
  const int gMM   = NT / 32;             // 1024 blocks
  const int gE    = NEDGE / 256;
  const int gN    = NT / 256;

  // init features
  k_init_feat<<<gElem, 256, 0, stream>>>(x1, cent1, rw1, demb, initW, initb, feat1);
  k_init_feat<<<gElem, 256, 0, stream>>>(x2, cent2, rw2, demb, initW, initb, feat2);

  // CSR + degree norms
  k_zero_i<<<gN, 256, 0, stream>>>(degi1, NT);
  k_zero_i<<<gN, 256, 0, stream>>>(degi2, NT);
  k_deg_count<<<gE, 256, 0, stream>>>(dst1, degi1);
  k_deg_count<<<gE, 256, 0, stream>>>(dst2, degi2);
  k_dinv<<<gN, 256, 0, stream>>>(degi1, dinv1, NT);
  k_dinv<<<gN, 256, 0, stream>>>(degi2, dinv2, NT);
  k_scan<<<1, 1024, 0, stream>>>(degi1, ofs1, cur1);
  k_scan<<<1, 1024, 0, stream>>>(degi2, ofs2, cur2);
  k_csr_fill<<<gE, 256, 0, stream>>>(src1, dst1, cur1, csr1);
  k_csr_fill<<<gE, 256, 0, stream>>>(src2, dst2, cur2, csr2);

  // -------- graph 1 conv chain
  k_mm<false><<<gMM, 256, 0, stream>>>(feat1, W1, htmp);
  k_conv<<<gElem, 256, 0, stream>>>(htmp, ofs1, cur1, csr1, dinv1, b1, tA);
  k_mm<true><<<gMM, 256, 0, stream>>>(tA, W2, htmp);
  k_conv<<<gElem, 256, 0, stream>>>(htmp, ofs1, cur1, csr1, dinv1, b2, tB);
  k_mm<true><<<gMM, 256, 0, stream>>>(tB, W3, htmp);
  k_conv<<<gElem, 256, 0, stream>>>(htmp, ofs1, cur1, csr1, dinv1, b3, f13);
  k_pool_sum4<<<BATCH * 4, 256, 0, stream>>>(feat1, tA, tB, f13, gfs);

  // -------- graph 2 conv chain
  k_mm<false><<<gMM, 256, 0, stream>>>(feat2, W1, htmp);
  k_conv<<<gElem, 256, 0, stream>>>(htmp, ofs2, cur2, csr2, dinv2, b1, tA);
  k_mm<true><<<gMM, 256, 0, stream>>>(tA, W2, htmp);
  k_conv<<<gElem, 256, 0, stream>>>(htmp, ofs2, cur2, csr2, dinv2, b2, tB);
  k_mm<true><<<gMM, 256, 0, stream>>>(tB, W3, htmp);
  k_conv<<<gElem, 256, 0, stream>>>(htmp, ofs2, cur2, csr2, dinv2, b3, f23);
  k_pool_max4<<<BATCH * 4, 256, 0, stream>>>(feat2, tA, tB, f23, gfs);

  // -------- sim1 (CSR scratch in S1 region no longer needed)
  k_mm<false><<<gMM, 256, 0, stream>>>(feat1, Aaff, htmp);   // Y = feat1 @ A
  k_affS<<<BATCH * 2, 256, 0, stream>>>(htmp, feat2, S1);
  k_sinkhorn<<<BATCH, 1024, 0, stream>>>(S1, topk);

  // -------- sim2
  k_mm<false><<<gMM, 256, 0, stream>>>(f13, Aaff, htmp);     // Y = f13 @ A
  k_affS<<<BATCH * 2, 256, 0, stream>>>(htmp, f23, S2);
  k_sinkhorn<<<BATCH, 1024, 0, stream>>>(S2, topk);

  // -------- ged
  k_mlp<<<BATCH, 256, 0, stream>>>(gfs, scW1, scb1, scW2, scb2, ged);
}

// Round 4
// 914.584 us; speedup vs baseline: 2.8377x; 1.1572x over previous
//
#include <hip/hip_runtime.h>
#include <math.h>

#define BATCH 256
#define NNODE 128
#define NT    32768      // BATCH*NNODE
#define FDIM  128
#define NEDGE 262144
#define LBL   29
#define MAXDEG 16
#define RWD   16
#define NTF   (NT * FDIM)   // 4194304 elements per feature matrix

// ---------------------------------------------------------------- init feat
__global__ __launch_bounds__(256) void k_init_feat(
    const float* __restrict__ x, const int* __restrict__ cent,
    const float* __restrict__ rw, const float* __restrict__ demb,
    const float* __restrict__ W, const float* __restrict__ b,
    float* __restrict__ out) {
  int gid = blockIdx.x * 256 + threadIdx.x;      // NT*FDIM threads
  int row = gid >> 7, f = gid & 127;
  const float* xr = x + row * LBL;
  const float* er = demb + cent[row] * MAXDEG;
  const float* rr = rw + row * RWD;
  float acc = b[f];
#pragma unroll
  for (int k = 0; k < LBL; ++k)    acc += xr[k] * W[k * FDIM + f];
#pragma unroll
  for (int k = 0; k < MAXDEG; ++k) acc += er[k] * W[(LBL + k) * FDIM + f];
#pragma unroll
  for (int k = 0; k < RWD; ++k)    acc += rr[k] * W[(LBL + MAXDEG + k) * FDIM + f];
  out[gid] = fmaxf(acc, 0.f);
}

// ---------------------------------------------------------------- CSR build
__global__ void k_zero_i(int* __restrict__ p, int n) {
  int i = blockIdx.x * 256 + threadIdx.x;
  if (i < n) p[i] = 0;
}
__global__ void k_deg_count(const int* __restrict__ dst, int* __restrict__ degi) {
  int e = blockIdx.x * 256 + threadIdx.x;
  if (e < NEDGE) atomicAdd(&degi[dst[e]], 1);
}
__global__ void k_dinv(const int* __restrict__ degi, float* __restrict__ dinv, int n) {
  int i = blockIdx.x * 256 + threadIdx.x;
  if (i < n) dinv[i] = rsqrtf((float)(degi[i] + 1));   // +1 self loop
}
__global__ __launch_bounds__(1024) void k_scan(const int* __restrict__ degi,
                                               int* __restrict__ ofs,
                                               int* __restrict__ cur) {
  __shared__ int part[1024];
  int t = threadIdx.x;
  int base = t * 32;
  int loc[32]; int sum = 0;
#pragma unroll
  for (int u = 0; u < 32; ++u) { loc[u] = sum; sum += degi[base + u]; }
  part[t] = sum;
  __syncthreads();
  for (int off = 1; off < 1024; off <<= 1) {
    int v = (t >= off) ? part[t - off] : 0;
    __syncthreads();
    part[t] += v;
    __syncthreads();
  }
  int excl = (t == 0) ? 0 : part[t - 1];
#pragma unroll
  for (int u = 0; u < 32; ++u) {
    int o = excl + loc[u];
    ofs[base + u] = o; cur[base + u] = o;
  }
}
__global__ void k_csr_fill(const int* __restrict__ src, const int* __restrict__ dst,
                           int* __restrict__ cur, int* __restrict__ csr) {
  int e = blockIdx.x * 256 + threadIdx.x;
  if (e < NEDGE) {
    int pos = atomicAdd(&cur[dst[e]], 1);
    csr[pos] = src[e];
  }
}

// ---------------------------------------------------------------- dense mm
// out (NT x 128) = relu?(A) (NT x 128) @ W (128 x 128)
// 64 rows/block (512 blocks), 256 thr, thread tile 4x8, A staged transposed
template <bool RELU_IN>
__global__ __launch_bounds__(256) void k_mm(const float* __restrict__ A,
                                            const float* __restrict__ W,
                                            float* __restrict__ out) {
  __shared__ float As[32][68];    // [k][row], padded
  __shared__ float Ws[32][132];   // [k][col], padded
  int t = threadIdx.x;
  int r0 = blockIdx.x * 64;
  int i0 = (t >> 4) * 4;          // 0..60
  int j0 = (t & 15) * 8;          // 0..120
  float acc[4][8] = {};
  for (int kc = 0; kc < FDIM; kc += 32) {
    __syncthreads();
    // stage A tile: 64 rows x 32 k, transposed, relu applied
#pragma unroll
    for (int qq = 0; qq < 2; ++qq) {
      int l = t + 256 * qq;
      int row = l >> 3, kq = (l & 7) << 2;
      float4 a = *reinterpret_cast<const float4*>(&A[(size_t)(r0 + row) * FDIM + kc + kq]);
      if (RELU_IN) {
        a.x = fmaxf(a.x, 0.f); a.y = fmaxf(a.y, 0.f);
        a.z = fmaxf(a.z, 0.f); a.w = fmaxf(a.w, 0.f);
      }
      As[kq + 0][row] = a.x; As[kq + 1][row] = a.y;
      As[kq + 2][row] = a.z; As[kq + 3][row] = a.w;
    }
    // stage W chunk: 32 k x 128 col
#pragma unroll
    for (int qq = 0; qq < 4; ++qq) {
      int l = t + 256 * qq;
      int row = l >> 5, c4 = (l & 31) << 2;
      *reinterpret_cast<float4*>(&Ws[row][c4]) =
          *reinterpret_cast<const float4*>(&W[(size_t)(kc + row) * FDIM + c4]);
    }
    __syncthreads();
#pragma unroll
    for (int kk = 0; kk < 32; ++kk) {
      float4 a4 = *reinterpret_cast<const float4*>(&As[kk][i0]);
      float4 wa = *reinterpret_cast<const float4*>(&Ws[kk][j0]);
      float4 wb = *reinterpret_cast<const float4*>(&Ws[kk][j0 + 4]);
      float av[4] = {a4.x, a4.y, a4.z, a4.w};
      float wv[8] = {wa.x, wa.y, wa.z, wa.w, wb.x, wb.y, wb.z, wb.w};
#pragma unroll
      for (int ii = 0; ii < 4; ++ii)
#pragma unroll
        for (int jj = 0; jj < 8; ++jj)
          acc[ii][jj] += av[ii] * wv[jj];
    }
  }
#pragma unroll
  for (int ii = 0; ii < 4; ++ii) {
    float4 o0 = make_float4(acc[ii][0], acc[ii][1], acc[ii][2], acc[ii][3]);
    float4 o1 = make_float4(acc[ii][4], acc[ii][5], acc[ii][6], acc[ii][7]);
    float* dst = &out[(size_t)(r0 + i0 + ii) * FDIM + j0];
    *reinterpret_cast<float4*>(dst) = o0;
    *reinterpret_cast<float4*>(dst + 4) = o1;
  }
}

// ---------------------------------------------------------------- gcn aggregate (CSR gather)
__global__ __launch_bounds__(256) void k_conv(
    const float* __restrict__ h, const int* __restrict__ ofs,
    const int* __restrict__ endp, const int* __restrict__ csr,
    const float* __restrict__ dinv, const float* __restrict__ b,
    float* __restrict__ out) {
  int gid = blockIdx.x * 256 + threadIdx.x;   // NT*128 threads
  int d = gid >> 7, f = gid & 127;
  float dd = dinv[d];
  float acc = dd * h[(size_t)d * FDIM + f];
  int e0 = ofs[d], e1 = endp[d];
  for (int j = e0; j < e1; ++j) {
    int s = csr[j];
    acc += dinv[s] * h[(size_t)s * FDIM + f];
  }
  out[gid] = b[f] + dd * acc;
}

// ---------------------------------------------------------------- fused pooling
__global__ __launch_bounds__(256) void k_pool_sum4(
    const float* __restrict__ m0, const float* __restrict__ m1,
    const float* __restrict__ m2, const float* __restrict__ m3,
    float* __restrict__ gfs) {
  __shared__ float part[256];
  int b = blockIdx.x >> 2, mi = blockIdx.x & 3;
  const float* m = (mi == 0) ? m0 : (mi == 1) ? m1 : (mi == 2) ? m2 : m3;
  int t = threadIdx.x;
  int c = t & 127, half = t >> 7;
  const float* base = m + (size_t)b * NNODE * FDIM + c;
  float s = 0.f;
  for (int n = half * 64; n < half * 64 + 64; ++n) s += base[n * FDIM];
  part[t] = s;
  __syncthreads();
  if (t < 128) gfs[b * 1024 + mi * 128 + t] = part[t] + part[t + 128];
}
__global__ __launch_bounds__(256) void k_pool_max4(
    const float* __restrict__ m0, const float* __restrict__ m1,
    const float* __restrict__ m2, const float* __restrict__ m3,
    float* __restrict__ gfs) {
  __shared__ float part[256];
  int b = blockIdx.x >> 2, mi = blockIdx.x & 3;
  const float* m = (mi == 0) ? m0 : (mi == 1) ? m1 : (mi == 2) ? m2 : m3;
  int t = threadIdx.x;
  int c = t & 127, half = t >> 7;
  const float* base = m + (size_t)b * NNODE * FDIM + c;
  float s = -INFINITY;
  for (int n = half * 64; n < half * 64 + 64; ++n) s = fmaxf(s, base[n * FDIM]);
  part[t] = s;
  __syncthreads();
  if (t < 128) gfs[b * 1024 + 512 + mi * 128 + t] = fmaxf(part[t], part[t + 128]);
}

// ---------------------------------------------------------------- affinity S[b] = Y[b] @ X[b]^T
__global__ __launch_bounds__(256) void k_affS(const float* __restrict__ Y,
                                              const float* __restrict__ X,
                                              float* __restrict__ S) {
  __shared__ float Ys[32][68];    // k-major, padded
  __shared__ float Xs[32][132];
  int t = threadIdx.x;
  int b = blockIdx.x >> 1;
  int ib = (blockIdx.x & 1) * 64;
  const float* Yb = Y + (size_t)b * NNODE * FDIM + (size_t)ib * FDIM;
  const float* Xb = X + (size_t)b * NNODE * FDIM;
  float* Sb = S + (size_t)b * NNODE * NNODE;
  int i0 = (t >> 4) * 4;          // 0..60
  int j0 = (t & 15) * 8;          // 0..120
  float acc[4][8] = {};
  for (int kc = 0; kc < FDIM; kc += 32) {
    __syncthreads();
#pragma unroll
    for (int qq = 0; qq < 2; ++qq) {
      int l = t + 256 * qq;
      int row = l >> 3, kq = (l & 7) << 2;
      float4 y = *reinterpret_cast<const float4*>(&Yb[(size_t)row * FDIM + kc + kq]);
      Ys[kq + 0][row] = y.x; Ys[kq + 1][row] = y.y;
      Ys[kq + 2][row] = y.z; Ys[kq + 3][row] = y.w;
    }
#pragma unroll
    for (int qq = 0; qq < 4; ++qq) {
      int l = t + 256 * qq;
      int row = l >> 3, kq = (l & 7) << 2;
      float4 xv = *reinterpret_cast<const float4*>(&Xb[(size_t)row * FDIM + kc + kq]);
      Xs[kq + 0][row] = xv.x; Xs[kq + 1][row] = xv.y;
      Xs[kq + 2][row] = xv.z; Xs[kq + 3][row] = xv.w;
    }
    __syncthreads();
#pragma unroll
    for (int kk = 0; kk < 32; ++kk) {
      float4 y4 = *reinterpret_cast<const float4*>(&Ys[kk][i0]);
      float4 xa = *reinterpret_cast<const float4*>(&Xs[kk][j0]);
      float4 xb = *reinterpret_cast<const float4*>(&Xs[kk][j0 + 4]);
      float yv[4] = {y4.x, y4.y, y4.z, y4.w};
      float xv[8] = {xa.x, xa.y, xa.z, xa.w, xb.x, xb.y, xb.z, xb.w};
#pragma unroll
      for (int ii = 0; ii < 4; ++ii)
#pragma unroll
        for (int jj = 0; jj < 8; ++jj)
          acc[ii][jj] += yv[ii] * xv[jj];
    }
  }
#pragma unroll
  for (int ii = 0; ii < 4; ++ii) {
    float4 o0 = make_float4(acc[ii][0], acc[ii][1], acc[ii][2], acc[ii][3]);
    float4 o1 = make_float4(acc[ii][4], acc[ii][5], acc[ii][6], acc[ii][7]);
    float* dst = &Sb[(size_t)(ib + i0 + ii) * NNODE + j0];
    *reinterpret_cast<float4*>(dst) = o0;
    *reinterpret_cast<float4*>(dst + 4) = o1;
  }
}

// ---------------------------------------------------------------- sinkhorn soft-topk (linear domain)
// p_i = exp(a_lo - x_i), q_i = exp(x_i - a_hi) are iteration-invariant.
// Iter: denom = p*E0 + q*E1; R0 = sum p/denom; R1 = sum q/denom;
//       E0' = (L-k)/R0; E1' = k/R1.
// prob_i = q_i*E1_final / (p_i*E0_prev + q_i*E1_prev)   [L*mu == 1]
__global__ __launch_bounds__(1024) void k_sinkhorn(float* __restrict__ S,
                                                   const int* __restrict__ topk) {
  const int L = NNODE * NNODE;           // 16384
  int b = blockIdx.x, t = threadIdx.x;
  int wave = t >> 6, lane = t & 63;
  float* x = S + (size_t)b * L;

  __shared__ float rA[16], rB[16];
  __shared__ float bc[2];

  float xv[16];
#pragma unroll
  for (int u = 0; u < 16; ++u) xv[u] = x[t + 1024 * u];

  // min / max of scores
  {
    float mn = xv[0], mx = xv[0];
#pragma unroll
    for (int u = 1; u < 16; ++u) { mn = fminf(mn, xv[u]); mx = fmaxf(mx, xv[u]); }
    for (int off = 32; off; off >>= 1) {
      mn = fminf(mn, __shfl_down(mn, off));
      mx = fmaxf(mx, __shfl_down(mx, off));
    }
    if (lane == 0) { rA[wave] = mn; rB[wave] = mx; }
    __syncthreads();
    if (t < 16) {
      mn = rA[t]; mx = rB[t];
      for (int off = 8; off; off >>= 1) {
        mn = fminf(mn, __shfl_down(mn, off));
        mx = fmaxf(mx, __shfl_down(mx, off));
      }
      if (t == 0) { bc[0] = mn - 1.f; bc[1] = mx + 1.f; }
    }
    __syncthreads();
  }
  float a_lo = bc[0], a_hi = bc[1];

  float p[16], q[16];
#pragma unroll
  for (int u = 0; u < 16; ++u) {
    p[u] = __expf(a_lo - xv[u]);
    q[u] = __expf(xv[u] - a_hi);
  }

  const float Lf = (float)L;
  float kk = 0.5f * (float)topk[0];

  float E0 = 1.f, E1 = 1.f, E0p = 1.f, E1p = 1.f;
  for (int it = 0; it < 6; ++it) {
    E0p = E0; E1p = E1;
    float r0 = 0.f, r1 = 0.f;
#pragma unroll
    for (int u = 0; u < 16; ++u) {
      float denom = fmaf(p[u], E0, q[u] * E1);
      float rin = __builtin_amdgcn_rcpf(denom);
      r0 = fmaf(p[u], rin, r0);
      r1 = fmaf(q[u], rin, r1);
    }
    for (int off = 32; off; off >>= 1) {
      r0 += __shfl_down(r0, off);
      r1 += __shfl_down(r1, off);
    }
    if (lane == 0) { rA[wave] = r0; rB[wave] = r1; }
    __syncthreads();
    if (t < 16) {
      r0 = rA[t]; r1 = rB[t];
      for (int off = 8; off; off >>= 1) {
        r0 += __shfl_down(r0, off);
        r1 += __shfl_down(r1, off);
      }
      if (t == 0) { bc[0] = (Lf - kk) / r0; bc[1] = kk / r1; }
    }
    __syncthreads();
    E0 = bc[0]; E1 = bc[1];
    __syncthreads();
  }

#pragma unroll
  for (int u = 0; u < 16; ++u) {
    float denom = fmaf(p[u], E0p, q[u] * E1p);
    x[t + 1024 * u] = q[u] * E1 * __builtin_amdgcn_rcpf(denom);
  }
}

// ---------------------------------------------------------------- scoring MLP
__global__ __launch_bounds__(256) void k_mlp(const float* __restrict__ gfs,
                                             const float* __restrict__ W1,
                                             const float* __restrict__ b1,
                                             const float* __restrict__ W2,
                                             const float* __restrict__ b2,
                                             float* __restrict__ ged) {
  __shared__ float sm[1024];
  int b = blockIdx.x, t = threadIdx.x;
  const float* s = gfs + b * 1024;
#pragma unroll
  for (int qq = 0; qq < 4; ++qq) sm[t + 256 * qq] = s[t + 256 * qq];
  __syncthreads();
  int j4 = (t & 15) * 4, kp = t >> 4;       // 16 j-quads x 16 k-partitions
  float4 acc = make_float4(0.f, 0.f, 0.f, 0.f);
#pragma unroll 8
  for (int k = 0; k < 64; ++k) {
    float4 w = *reinterpret_cast<const float4*>(&W1[(size_t)(kp * 64 + k) * 64 + j4]);
    float sv = sm[kp * 64 + k];
    acc.x += sv * w.x; acc.y += sv * w.y; acc.z += sv * w.z; acc.w += sv * w.w;
  }
  __syncthreads();
  *reinterpret_cast<float4*>(&sm[kp * 64 + j4]) = acc;   // reuse sm as part[16][64]
  __syncthreads();
  if (t < 64) {
    float h = b1[t];
#pragma unroll
    for (int kp2 = 0; kp2 < 16; ++kp2) h += sm[kp2 * 64 + t];
    h = fmaxf(h, 0.f);
    float v = h * W2[t];
    for (int off = 32; off; off >>= 1) v += __shfl_down(v, off);
    if (t == 0) ged[b] = 1.f / (1.f + __expf(-(v + b2[0])));
  }
}

// ================================================================ launch
extern "C" void kernel_launch(void* const* d_in, const int* in_sizes, int n_in,
                              void* d_out, int out_size, void* d_ws, size_t ws_size,
                              hipStream_t stream) {
  (void)in_sizes; (void)n_in; (void)out_size; (void)ws_size;
  const float* x1    = (const float*)d_in[0];
  const int*   cent1 = (const int*)  d_in[1];
  const float* rw1   = (const float*)d_in[2];
  const int*   src1  = (const int*)  d_in[3];
  const int*   dst1  = (const int*)  d_in[4];
  const float* x2    = (const float*)d_in[5];
  const int*   cent2 = (const int*)  d_in[6];
  const float* rw2   = (const float*)d_in[7];
  const int*   src2  = (const int*)  d_in[8];
  const int*   dst2  = (const int*)  d_in[9];
  const float* demb  = (const float*)d_in[10];
  const float* initW = (const float*)d_in[11];
  const float* initb = (const float*)d_in[12];
  const float* W1    = (const float*)d_in[13];
  const float* b1    = (const float*)d_in[14];
  const float* W2    = (const float*)d_in[15];
  const float* b2    = (const float*)d_in[16];
  const float* W3    = (const float*)d_in[17];
  const float* b3    = (const float*)d_in[18];
  const float* Aaff  = (const float*)d_in[19];
  const float* scW1  = (const float*)d_in[20];
  const float* scb1  = (const float*)d_in[21];
  const float* scW2  = (const float*)d_in[22];
  const float* scb2  = (const float*)d_in[23];
  const int*   topk  = (const int*)  d_in[24];

  float* ws    = (float*)d_ws;
  float* feat1 = ws;
  float* feat2 = ws + (size_t)1 * NTF;
  float* tA    = ws + (size_t)2 * NTF;
  float* tB    = ws + (size_t)3 * NTF;
  float* f13   = ws + (size_t)4 * NTF;
  float* f23   = ws + (size_t)5 * NTF;
  float* htmp  = ws + (size_t)6 * NTF;   // also reused as Y
  float* dinv1 = ws + (size_t)7 * NTF;
  float* dinv2 = dinv1 + NT;
  float* gfs   = dinv2 + NT;             // 256*1024

  float* ged = (float*)d_out;
  float* S1  = ged + BATCH;
  float* S2  = S1 + (size_t)BATCH * NNODE * NNODE;

  // int scratch lives in S1's output region (only written by affS AFTER convs)
  int* degi1 = (int*)S1;
  int* ofs1  = degi1 + NT;
  int* cur1  = ofs1 + NT;
  int* csr1  = cur1 + NT;
  int* degi2 = csr1 + NEDGE;
  int* ofs2  = degi2 + NT;
  int* cur2  = ofs2 + NT;
  int* csr2  = cur2 + NT;

  const int gElem = NT * FDIM / 256;     // 16384 blocks
  const int gMM   = NT / 64;             // 512 blocks
  const int gE    = NEDGE / 256;
  const int gN    = NT / 256;

  // init features
  k_init_feat<<<gElem, 256, 0, stream>>>(x1, cent1, rw1, demb, initW, initb, feat1);
  k_init_feat<<<gElem, 256, 0, stream>>>(x2, cent2, rw2, demb, initW, initb, feat2);

  // CSR + degree norms
  k_zero_i<<<gN, 256, 0, stream>>>(degi1, NT);
  k_zero_i<<<gN, 256, 0, stream>>>(degi2, NT);
  k_deg_count<<<gE, 256, 0, stream>>>(dst1, degi1);
  k_deg_count<<<gE, 256, 0, stream>>>(dst2, degi2);
  k_dinv<<<gN, 256, 0, stream>>>(degi1, dinv1, NT);
  k_dinv<<<gN, 256, 0, stream>>>(degi2, dinv2, NT);
  k_scan<<<1, 1024, 0, stream>>>(degi1, ofs1, cur1);
  k_scan<<<1, 1024, 0, stream>>>(degi2, ofs2, cur2);
  k_csr_fill<<<gE, 256, 0, stream>>>(src1, dst1, cur1, csr1);
  k_csr_fill<<<gE, 256, 0, stream>>>(src2, dst2, cur2, csr2);

  // -------- graph 1 conv chain
  k_mm<false><<<gMM, 256, 0, stream>>>(feat1, W1, htmp);
  k_conv<<<gElem, 256, 0, stream>>>(htmp, ofs1, cur1, csr1, dinv1, b1, tA);
  k_mm<true><<<gMM, 256, 0, stream>>>(tA, W2, htmp);
  k_conv<<<gElem, 256, 0, stream>>>(htmp, ofs1, cur1, csr1, dinv1, b2, tB);
  k_mm<true><<<gMM, 256, 0, stream>>>(tB, W3, htmp);
  k_conv<<<gElem, 256, 0, stream>>>(htmp, ofs1, cur1, csr1, dinv1, b3, f13);
  k_pool_sum4<<<BATCH * 4, 256, 0, stream>>>(feat1, tA, tB, f13, gfs);

  // -------- graph 2 conv chain
  k_mm<false><<<gMM, 256, 0, stream>>>(feat2, W1, htmp);
  k_conv<<<gElem, 256, 0, stream>>>(htmp, ofs2, cur2, csr2, dinv2, b1, tA);
  k_mm<true><<<gMM, 256, 0, stream>>>(tA, W2, htmp);
  k_conv<<<gElem, 256, 0, stream>>>(htmp, ofs2, cur2, csr2, dinv2, b2, tB);
  k_mm<true><<<gMM, 256, 0, stream>>>(tB, W3, htmp);
  k_conv<<<gElem, 256, 0, stream>>>(htmp, ofs2, cur2, csr2, dinv2, b3, f23);
  k_pool_max4<<<BATCH * 4, 256, 0, stream>>>(feat2, tA, tB, f23, gfs);

  // -------- sim1 (CSR scratch in S1 region no longer needed)
  k_mm<false><<<gMM, 256, 0, stream>>>(feat1, Aaff, htmp);   // Y = feat1 @ A
  k_affS<<<BATCH * 2, 256, 0, stream>>>(htmp, feat2, S1);
  k_sinkhorn<<<BATCH, 1024, 0, stream>>>(S1, topk);

  // -------- sim2
  k_mm<false><<<gMM, 256, 0, stream>>>(f13, Aaff, htmp);     // Y = f13 @ A
  k_affS<<<BATCH * 2, 256, 0, stream>>>(htmp, f23, S2);
  k_sinkhorn<<<BATCH, 1024, 0, stream>>>(S2, topk);

  // -------- ged
  k_mlp<<<BATCH, 256, 0, stream>>>(gfs, scW1, scb1, scW2, scb2, ged);
}